// Round 14
// baseline (1321.300 us; speedup 1.0000x reference)
//
#include <hip/hip_runtime.h>
#include <hip/hip_bf16.h>

typedef short bf4 __attribute__((ext_vector_type(4)));
typedef short short8 __attribute__((ext_vector_type(8)));
typedef float f32x4 __attribute__((ext_vector_type(4)));

#define MFMA(a, b, c) __builtin_amdgcn_mfma_f32_16x16x32_bf16((a), (b), (c), 0, 0, 0)

#define NB 2
#define NS 1024
#define NHID 768
#define NHEAD 12
#define NDH 64

// Diagnostic reps: push every kernel past the ~330us fill floor.
#define REP_CVT 100
#define REP_QKV 24
#define REP_BIAS 4
#define REP_ATTN 10

__device__ __forceinline__ short f2bf(float x) {
    __hip_bfloat16 h = __float2bfloat16(x);
    return *reinterpret_cast<short*>(&h);
}

__device__ __forceinline__ int xcd_swz(int orig, int nwg) {
    return (orig & 7) * (nwg >> 3) + (orig >> 3);
}

typedef const __attribute__((address_space(1))) void gas_t;
typedef __attribute__((address_space(3))) void las_t;
__device__ __forceinline__ void gld_lds16(const float* g, float* l) {
    __builtin_amdgcn_global_load_lds((gas_t*)g, (las_t*)l, 16, 0, 0);
}
__device__ __forceinline__ void gld_lds16s(const short* g, short* l) {
    __builtin_amdgcn_global_load_lds((gas_t*)g, (las_t*)l, 16, 0, 0);
}

// ---------------------------------------------------------------------------
// Kernel 0: convert hidden + Wq/Wk/Wv to bf16 (repped).
// ---------------------------------------------------------------------------
#define NHE (2048 * 768)
#define WE  (768 * 768)
__global__ void cvt_bf16_all(
    const float* __restrict__ hidden,
    const float* __restrict__ Wq, const float* __restrict__ Wk,
    const float* __restrict__ Wv,
    short* __restrict__ Xbf, short* __restrict__ Wbf)
{
    const int base = (blockIdx.x * 256 + threadIdx.x) * 4;
    const float* src; short* dst; int off;
    if (base < NHE)               { src = hidden; dst = Xbf;          off = base; }
    else if (base < NHE + WE)     { src = Wq;     dst = Wbf;          off = base - NHE; }
    else if (base < NHE + 2 * WE) { src = Wk;     dst = Wbf + WE;     off = base - NHE - WE; }
    else                          { src = Wv;     dst = Wbf + 2 * WE; off = base - NHE - 2 * WE; }
    for (int rep = 0; rep < REP_CVT; ++rep) {
        f32x4 v = *reinterpret_cast<const f32x4*>(src + off);
        bf4 r;
        r[0] = f2bf(v[0]); r[1] = f2bf(v[1]); r[2] = f2bf(v[2]); r[3] = f2bf(v[3]);
        *reinterpret_cast<bf4*>(dst + off) = r;
        __syncthreads();
    }
}

// ---------------------------------------------------------------------------
// Kernel 1: QKV GEMM, LDS-staged + XCD swizzle (repped).
// ---------------------------------------------------------------------------
__global__ __launch_bounds__(256, 3) void qkv_gemm(
    const short* __restrict__ Xbf, const short* __restrict__ Wbf,
    const float* __restrict__ bq, const float* __restrict__ bk,
    const float* __restrict__ bv,
    short* __restrict__ Qo, short* __restrict__ Ko, short* __restrict__ VTo)
{
    const int lane = threadIdx.x & 63;
    const int wave = threadIdx.x >> 6;
    const int lg = lane >> 4, lr = lane & 15;

    const int wgid = xcd_swz(blockIdx.x, 16 * 36);
    const int m0 = (wgid / 36) * 128;
    const int n0 = (wgid % 36) * 64;
    const int proj = n0 / NHID;
    const int ncol0 = n0 % NHID;
    const float* bias = proj == 0 ? bq : (proj == 1 ? bk : bv);

    __shared__ short Alds[2][128 * 64];
    __shared__ short Blds[2][64 * 64];

    auto stage = [&](int t, int buf) {
        const int k0 = t * 64;
        #pragma unroll
        for (int p = 0; p < 4; ++p) {
            const int op = wave * 4 + p;
            const int unit = op * 64 + lane;
            const int r = unit >> 3, u = unit & 7;
            const int g = u ^ (r & 7);
            gld_lds16s(Xbf + (size_t)(m0 + r) * NHID + k0 + g * 8,
                       &Alds[buf][op * 512]);
        }
        #pragma unroll
        for (int p = 0; p < 2; ++p) {
            const int op = wave * 2 + p;
            const int unit = op * 64 + lane;
            const int r = unit >> 3, u = unit & 7;
            const int g = u ^ (r & 7);
            gld_lds16s(Wbf + (size_t)(n0 + r) * NHID + k0 + g * 8,
                       &Blds[buf][op * 512]);
        }
    };

    for (int rep = 0; rep < REP_QKV; ++rep) {
        asm volatile("s_waitcnt vmcnt(0) lgkmcnt(0)" ::: "memory");
        __syncthreads();

        f32x4 acc[2][4];
        #pragma unroll
        for (int mm = 0; mm < 2; ++mm)
            #pragma unroll
            for (int s = 0; s < 4; ++s) acc[mm][s] = (f32x4){0.f, 0.f, 0.f, 0.f};

        auto compute = [&](int buf) {
            #pragma unroll
            for (int kk = 0; kk < 2; ++kk) {
                const int U = kk * 4 + lg;
                short8 a[2];
                #pragma unroll
                for (int mm = 0; mm < 2; ++mm) {
                    const int R = wave * 32 + mm * 16 + lr;
                    a[mm] = *reinterpret_cast<const short8*>(
                        &Alds[buf][(R * 8 + (U ^ (R & 7))) * 8]);
                }
                #pragma unroll
                for (int s = 0; s < 4; ++s) {
                    const int R = s * 16 + lr;
                    short8 b = *reinterpret_cast<const short8*>(
                        &Blds[buf][(R * 8 + (U ^ (R & 7))) * 8]);
                    acc[0][s] = MFMA(a[0], b, acc[0][s]);
                    acc[1][s] = MFMA(a[1], b, acc[1][s]);
                }
            }
        };

        stage(0, 0);
        #pragma unroll 2
        for (int t = 0; t < 12; ++t) {
            const int buf = t & 1;
            asm volatile("s_waitcnt vmcnt(0)" ::: "memory");
            __syncthreads();
            if (t < 11) stage(t + 1, buf ^ 1);
            compute(buf);
        }

        #pragma unroll
        for (int mm = 0; mm < 2; ++mm) {
            #pragma unroll
            for (int s = 0; s < 4; ++s) {
                const int ncol = ncol0 + s * 16 + lr;
                const float badd = bias[ncol];
                #pragma unroll
                for (int r = 0; r < 4; ++r) {
                    const int m = m0 + wave * 32 + mm * 16 + lg * 4 + r;
                    const short v16 = f2bf(acc[mm][s][r] + badd);
                    if (proj == 0) {
                        Qo[(size_t)m * NHID + ncol] = v16;
                    } else if (proj == 1) {
                        Ko[(size_t)m * NHID + ncol] = v16;
                    } else {
                        const int b = m >> 10, ss = m & 1023;
                        const int h = ncol >> 6, dd = ncol & 63;
                        VTo[(((size_t)(b * NHEAD + h) * NDH + dd) << 10) + ss] = v16;
                    }
                }
            }
        }
    }
}

// ---------------------------------------------------------------------------
// Kernel 2: bias GEMM -> bf16 pre-scaled + mask folded (repped).
// ---------------------------------------------------------------------------
__global__ __launch_bounds__(256, 2) void bias_gemm(
    const short* __restrict__ Q,
    const float* __restrict__ bbox,
    const float* __restrict__ mask,
    short* __restrict__ biasH)
{
    const int lane = threadIdx.x & 63;
    const int wave = threadIdx.x >> 6;
    const int lg = lane >> 4, lr = lane & 15;
    const int i = blockIdx.x;
    const int jq = wave * 256;

    __shared__ float lds[4][2][2048];

    short8 qa[2][2];
    #pragma unroll
    for (int b2 = 0; b2 < 2; ++b2)
        #pragma unroll
        for (int kk = 0; kk < 2; ++kk)
            qa[b2][kk] = *reinterpret_cast<const short8*>(
                Q + ((size_t)(b2 * NS) + i) * NHID + lr * 64 + kk * 32 + lg * 8);

    const int r_half = lane >> 5;
    const int u_lin = lane & 31;

    auto stage = [&](int t, int buf) {
        const int j0 = jq + t * 16;
        float* dst = &lds[wave][buf][0];
        #pragma unroll
        for (int w = 0; w < 8; ++w) {
            const int r = 2 * w + r_half;
            const int u = u_lin ^ (r & 7);
            const float* src = bbox + (size_t)(i * NS + j0 + r) * 128 + u * 4;
            gld_lds16(src, dst + w * 256);
        }
    };

    auto compute = [&](int t, int buf) {
        const float* tile = &lds[wave][buf][0];
        const int j0 = jq + t * 16;
        const int x = lr & 7;
        #pragma unroll
        for (int b2 = 0; b2 < 2; ++b2) {
            const float mk = mask[b2 * NS + j0 + lr];
            f32x4 c = (f32x4){0.f, 0.f, 0.f, 0.f};
            #pragma unroll
            for (int kk = 0; kk < 2; ++kk) {
                const int q0 = b2 * 16 + kk * 8 + lg * 2;
                f32x4 ca = *reinterpret_cast<const f32x4*>(tile + (size_t)(lr * 32 + ((q0)     ^ x)) * 4);
                f32x4 cb = *reinterpret_cast<const f32x4*>(tile + (size_t)(lr * 32 + ((q0 + 1) ^ x)) * 4);
                short8 bf;
                bf[0] = f2bf(ca[0]); bf[1] = f2bf(ca[1]); bf[2] = f2bf(ca[2]); bf[3] = f2bf(ca[3]);
                bf[4] = f2bf(cb[0]); bf[5] = f2bf(cb[1]); bf[6] = f2bf(cb[2]); bf[7] = f2bf(cb[3]);
                c = MFMA(qa[b2][kk], bf, c);
            }
            if (lg < 3) {
                #pragma unroll
                for (int r = 0; r < 4; ++r) {
                    const int n = lg * 4 + r;
                    biasH[((size_t)(b2 * NHEAD + n) * NS + i) * NS + j0 + lr] =
                        f2bf(c[r] * 0.125f + mk);
                }
            }
        }
    };

    for (int rep = 0; rep < REP_BIAS; ++rep) {
        asm volatile("s_waitcnt vmcnt(0) lgkmcnt(0)" ::: "memory");
        stage(0, 0);
        for (int t = 0; t < 16; ++t) {
            const int buf = t & 1;
            asm volatile("s_waitcnt lgkmcnt(0)" ::: "memory");
            if (t < 15) stage(t + 1, buf ^ 1);
            if (t == 0 || t == 15) asm volatile("s_waitcnt vmcnt(8)"  ::: "memory");
            else                   asm volatile("s_waitcnt vmcnt(16)" ::: "memory");
            compute(t, buf);
        }
    }
}

// ---------------------------------------------------------------------------
// Kernel 3: attn3 LDS-staged (repped).
// ---------------------------------------------------------------------------
__global__ __launch_bounds__(256, 3) void attn3(
    const short* __restrict__ Q,
    const short* __restrict__ K,
    const short* __restrict__ VT,
    const short* __restrict__ biasH,
    float* __restrict__ out)
{
    const int tid = threadIdx.x;
    const int lane = tid & 63;
    const int wave = tid >> 6;
    const int lg = lane >> 4, lr = lane & 15;

    const int wgid = xcd_swz(blockIdx.x, 24 * 16);
    const int bh = wgid >> 4;
    const int ic = wgid & 15;
    const int b = bh / NHEAD, h = bh % NHEAD;
    const int i0 = ic * 64 + wave * 16;

    __shared__ short Klds[2][2048];
    __shared__ short Vlds[2][2048];
    __shared__ short Blds[2][2048];
    __shared__ short plds[4][16 * 40];

    short8 qa[2];
    #pragma unroll
    for (int kk = 0; kk < 2; ++kk)
        qa[kk] = *reinterpret_cast<const short8*>(
            Q + ((size_t)(b * NS) + i0 + lr) * NHID + h * 64 + kk * 32 + lg * 8);

    const short* Kb = K + (size_t)b * NS * NHID + h * 64;
    const short* Vb = VT + (size_t)(b * NHEAD + h) * NDH * NS;
    const short* Bb = biasH + ((size_t)(b * NHEAD + h) * NS + ic * 64) * NS;

    const int kr = tid >> 3, ku = tid & 7;
    const int kgu = ku ^ (kr & 7);
    const int vr = tid >> 2, vu = tid & 3;
    const int vgu = vu ^ (vr & 3);
    const int br = tid >> 2, bu = tid & 3;

    auto stage = [&](int t, int buf) {
        const int j0 = t * 32;
        gld_lds16s(Kb + (size_t)(j0 + kr) * NHID + kgu * 8, &Klds[buf][tid * 8]);
        gld_lds16s(Vb + (size_t)vr * NS + j0 + vgu * 8,     &Vlds[buf][tid * 8]);
        gld_lds16s(Bb + (size_t)br * NS + j0 + bu * 8,      &Blds[buf][tid * 8]);
    };

    for (int rep = 0; rep < REP_ATTN; ++rep) {
        asm volatile("s_waitcnt vmcnt(0) lgkmcnt(0)" ::: "memory");
        __syncthreads();

        f32x4 ctx[4];
        #pragma unroll
        for (int dt = 0; dt < 4; ++dt) ctx[dt] = (f32x4){0.f, 0.f, 0.f, 0.f};
        f32x4 den = (f32x4){0.f, 0.f, 0.f, 0.f};

        auto compute = [&](int buf) {
            f32x4 sc[2];
            #pragma unroll
            for (int s = 0; s < 2; ++s) {
                f32x4 c = (f32x4){0.f, 0.f, 0.f, 0.f};
                #pragma unroll
                for (int kk = 0; kk < 2; ++kk) {
                    const int R = s * 16 + lr;
                    const int U = kk * 4 + lg;
                    short8 kf = *reinterpret_cast<const short8*>(
                        &Klds[buf][(R * 8 + (U ^ (R & 7))) * 8]);
                    c = MFMA(qa[kk], kf, c);
                }
                sc[s] = c;
            }
            #pragma unroll
            for (int s = 0; s < 2; ++s)
                #pragma unroll
                for (int r = 0; r < 4; ++r) {
                    const unsigned int u = (unsigned int)(unsigned short)
                        Blds[buf][wave * 512 + (lg * 4 + r) * 32 + s * 16 + lr] << 16;
                    float bb;
                    __builtin_memcpy(&bb, &u, 4);
                    sc[s][r] = __expf(sc[s][r] * 0.125f + bb);
                }
            den += sc[0] + sc[1];

            #pragma unroll
            for (int s = 0; s < 2; ++s)
                #pragma unroll
                for (int r = 0; r < 4; ++r)
                    plds[wave][(lg * 4 + r) * 40 + s * 16 + lr] = f2bf(sc[s][r]);
            asm volatile("" ::: "memory");
            short8 pa = *reinterpret_cast<const short8*>(&plds[wave][lr * 40 + lg * 8]);
            asm volatile("" ::: "memory");

            #pragma unroll
            for (int dt = 0; dt < 4; ++dt) {
                const int R = dt * 16 + lr;
                short8 vf = *reinterpret_cast<const short8*>(
                    &Vlds[buf][(R * 4 + (lg ^ (R & 3))) * 8]);
                ctx[dt] = MFMA(pa, vf, ctx[dt]);
            }
        };

        stage(0, 0);
        for (int t = 0; t < 32; ++t) {
            const int buf = t & 1;
            asm volatile("s_waitcnt vmcnt(0)" ::: "memory");
            __syncthreads();
            if (t < 31) stage(t + 1, buf ^ 1);
            compute(buf);
        }

        #pragma unroll
        for (int w = 1; w < 16; w <<= 1) {
            f32x4 o;
            #pragma unroll
            for (int r = 0; r < 4; ++r) o[r] = __shfl_xor(den[r], w, 64);
            den += o;
        }

        #pragma unroll
        for (int r = 0; r < 4; ++r) {
            const float inv = 1.0f / den[r];
            const int i = i0 + lg * 4 + r;
            #pragma unroll
            for (int dt = 0; dt < 4; ++dt)
                out[((size_t)(b * NS) + i) * NHID + h * 64 + dt * 16 + lr] =
                    ctx[dt][r] * inv;
        }
    }
}

extern "C" void kernel_launch(void* const* d_in, const int* in_sizes, int n_in,
                              void* d_out, int out_size, void* d_ws, size_t ws_size,
                              hipStream_t stream) {
    (void)in_sizes; (void)n_in; (void)out_size; (void)ws_size;
    const float* hidden = (const float*)d_in[0];
    const float* bbox   = (const float*)d_in[1];
    const float* mask   = (const float*)d_in[2];
    const float* Wq = (const float*)d_in[3]; const float* bq = (const float*)d_in[4];
    const float* Wk = (const float*)d_in[5]; const float* bk = (const float*)d_in[6];
    const float* Wv = (const float*)d_in[7]; const float* bv = (const float*)d_in[8];
    float* out = (float*)d_out;

    char* ws = (char*)d_ws;
    const size_t qkv_bytes = (size_t)NB * NS * NHID * sizeof(short);
    short* Qw  = (short*)ws;
    short* Kw  = (short*)(ws + qkv_bytes);
    short* VTw = (short*)(ws + 2 * qkv_bytes);
    short* biasH = (short*)(ws + 3 * qkv_bytes);
    const size_t bias_bytes = (size_t)NB * NHEAD * NS * NS * sizeof(short);
    short* Xbf = (short*)(ws + 3 * qkv_bytes + bias_bytes);
    short* Wbf = Xbf + (size_t)2048 * NHID;

    const int cvt_total = (NHE + 3 * WE) / 4;
    cvt_bf16_all<<<cvt_total / 256, 256, 0, stream>>>(hidden, Wq, Wk, Wv, Xbf, Wbf);

    qkv_gemm<<<16 * 36, 256, 0, stream>>>(Xbf, Wbf, bq, bk, bv, Qw, Kw, VTw);

    bias_gemm<<<NS, 256, 0, stream>>>(Qw, bbox, mask, biasH);

    attn3<<<24 * 16, 256, 0, stream>>>(Qw, Kw, VTw, biasH, out);
}

// Round 15
// 207.874 us; speedup vs baseline: 6.3563x; 6.3563x over previous
//
#include <hip/hip_runtime.h>
#include <hip/hip_bf16.h>

typedef short bf4 __attribute__((ext_vector_type(4)));
typedef short short8 __attribute__((ext_vector_type(8)));
typedef float f32x4 __attribute__((ext_vector_type(4)));

#define MFMA(a, b, c) __builtin_amdgcn_mfma_f32_16x16x32_bf16((a), (b), (c), 0, 0, 0)

#define NB 2
#define NS 1024
#define NHID 768
#define NHEAD 12
#define NDH 64

__device__ __forceinline__ short f2bf(float x) {
    __hip_bfloat16 h = __float2bfloat16(x);
    return *reinterpret_cast<short*>(&h);
}

__device__ __forceinline__ int xcd_swz(int orig, int nwg) {
    return (orig & 7) * (nwg >> 3) + (orig >> 3);
}

typedef const __attribute__((address_space(1))) void gas_t;
typedef __attribute__((address_space(3))) void las_t;
__device__ __forceinline__ void gld_lds16(const float* g, float* l) {
    __builtin_amdgcn_global_load_lds((gas_t*)g, (las_t*)l, 16, 0, 0);
}
__device__ __forceinline__ void gld_lds16s(const short* g, short* l) {
    __builtin_amdgcn_global_load_lds((gas_t*)g, (las_t*)l, 16, 0, 0);
}

// ---------------------------------------------------------------------------
// Kernel 0: convert hidden + Wq/Wk/Wv to bf16 (once).
// ---------------------------------------------------------------------------
#define NHE (2048 * 768)
#define WE  (768 * 768)
__global__ void cvt_bf16_all(
    const float* __restrict__ hidden,
    const float* __restrict__ Wq, const float* __restrict__ Wk,
    const float* __restrict__ Wv,
    short* __restrict__ Xbf, short* __restrict__ Wbf)
{
    const int base = (blockIdx.x * 256 + threadIdx.x) * 4;
    const float* src; short* dst; int off;
    if (base < NHE)               { src = hidden; dst = Xbf;          off = base; }
    else if (base < NHE + WE)     { src = Wq;     dst = Wbf;          off = base - NHE; }
    else if (base < NHE + 2 * WE) { src = Wk;     dst = Wbf + WE;     off = base - NHE - WE; }
    else                          { src = Wv;     dst = Wbf + 2 * WE; off = base - NHE - 2 * WE; }
    f32x4 v = *reinterpret_cast<const f32x4*>(src + off);
    bf4 r;
    r[0] = f2bf(v[0]); r[1] = f2bf(v[1]); r[2] = f2bf(v[2]); r[3] = f2bf(v[3]);
    *reinterpret_cast<bf4*>(dst + off) = r;
}

// ---------------------------------------------------------------------------
// Kernel 1: QKV GEMM v3. BM=64 BN=64 BK=64, grid 1152 (4.5 blocks/CU).
// 3-buffer LDS rotation + counted vmcnt + raw s_barrier: stage(t+1) stays in
// flight across the barrier; compute(t-1) covers stage(t)'s latency.
// Race-free: buf (t+1)%3's last reader is compute(t-2), separated by
// barrier(t-1) from stage(t+1).
// ---------------------------------------------------------------------------
__global__ __launch_bounds__(256, 3) void qkv_gemm(
    const short* __restrict__ Xbf, const short* __restrict__ Wbf,
    const float* __restrict__ bq, const float* __restrict__ bk,
    const float* __restrict__ bv,
    short* __restrict__ Qo, short* __restrict__ Ko, short* __restrict__ VTo)
{
    const int lane = threadIdx.x & 63;
    const int wave = threadIdx.x >> 6;
    const int lg = lane >> 4, lr = lane & 15;

    const int wgid = xcd_swz(blockIdx.x, 32 * 36);
    const int m0 = (wgid / 36) * 64;
    const int n0 = (wgid % 36) * 64;
    const int proj = n0 / NHID;
    const int ncol0 = n0 % NHID;
    const float* bias = proj == 0 ? bq : (proj == 1 ? bk : bv);

    __shared__ short Alds[3][64 * 64];   // 8KB per buf
    __shared__ short Blds[3][64 * 64];   // 8KB per buf

    f32x4 acc[4];
    #pragma unroll
    for (int s = 0; s < 4; ++s) acc[s] = (f32x4){0.f, 0.f, 0.f, 0.f};

    auto stage = [&](int t, int buf) {
        const int k0 = t * 64;
        #pragma unroll
        for (int p = 0; p < 2; ++p) {
            const int op = wave * 2 + p;
            const int unit = op * 64 + lane;
            const int r = unit >> 3, u = unit & 7;
            const int g = u ^ (r & 7);
            gld_lds16s(Xbf + (size_t)(m0 + r) * NHID + k0 + g * 8,
                       &Alds[buf][op * 512]);
        }
        #pragma unroll
        for (int p = 0; p < 2; ++p) {
            const int op = wave * 2 + p;
            const int unit = op * 64 + lane;
            const int r = unit >> 3, u = unit & 7;
            const int g = u ^ (r & 7);
            gld_lds16s(Wbf + (size_t)(n0 + r) * NHID + k0 + g * 8,
                       &Blds[buf][op * 512]);
        }
    };

    auto compute = [&](int buf) {
        #pragma unroll
        for (int kk = 0; kk < 2; ++kk) {
            const int U = kk * 4 + lg;
            const int Ra = wave * 16 + lr;
            short8 a = *reinterpret_cast<const short8*>(
                &Alds[buf][(Ra * 8 + (U ^ (Ra & 7))) * 8]);
            #pragma unroll
            for (int s = 0; s < 4; ++s) {
                const int R = s * 16 + lr;
                short8 b = *reinterpret_cast<const short8*>(
                    &Blds[buf][(R * 8 + (U ^ (R & 7))) * 8]);
                acc[s] = MFMA(a, b, acc[s]);
            }
        }
    };

    stage(0, 0);
    for (int t = 0; t < 12; ++t) {
        if (t < 11) {
            stage(t + 1, (t + 1) % 3);
            asm volatile("s_waitcnt vmcnt(4)" ::: "memory");
        } else {
            asm volatile("s_waitcnt vmcnt(0)" ::: "memory");
        }
        __builtin_amdgcn_s_barrier();
        compute(t % 3);
    }

    #pragma unroll
    for (int s = 0; s < 4; ++s) {
        const int ncol = ncol0 + s * 16 + lr;
        const float badd = bias[ncol];
        #pragma unroll
        for (int r = 0; r < 4; ++r) {
            const int m = m0 + wave * 16 + lg * 4 + r;
            const short v16 = f2bf(acc[s][r] + badd);
            if (proj == 0) {
                Qo[(size_t)m * NHID + ncol] = v16;
            } else if (proj == 1) {
                Ko[(size_t)m * NHID + ncol] = v16;
            } else {
                const int b = m >> 10, ss = m & 1023;
                const int h = ncol >> 6, dd = ncol & 63;
                VTo[(((size_t)(b * NHEAD + h) * NDH + dd) << 10) + ss] = v16;
            }
        }
    }
}

// ---------------------------------------------------------------------------
// Kernel 2: bias GEMM -> bf16 pre-scaled + mask folded (at roofline: 97us
// vs (512+50)MB/6.3 = 89us floor). Unchanged.
// ---------------------------------------------------------------------------
__global__ __launch_bounds__(256, 2) void bias_gemm(
    const short* __restrict__ Q,
    const float* __restrict__ bbox,
    const float* __restrict__ mask,
    short* __restrict__ biasH)
{
    const int lane = threadIdx.x & 63;
    const int wave = threadIdx.x >> 6;
    const int lg = lane >> 4, lr = lane & 15;
    const int i = blockIdx.x;
    const int jq = wave * 256;

    __shared__ float lds[4][2][2048];

    short8 qa[2][2];
    #pragma unroll
    for (int b2 = 0; b2 < 2; ++b2)
        #pragma unroll
        for (int kk = 0; kk < 2; ++kk)
            qa[b2][kk] = *reinterpret_cast<const short8*>(
                Q + ((size_t)(b2 * NS) + i) * NHID + lr * 64 + kk * 32 + lg * 8);

    const int r_half = lane >> 5;
    const int u_lin = lane & 31;

    auto stage = [&](int t, int buf) {
        const int j0 = jq + t * 16;
        float* dst = &lds[wave][buf][0];
        #pragma unroll
        for (int w = 0; w < 8; ++w) {
            const int r = 2 * w + r_half;
            const int u = u_lin ^ (r & 7);
            const float* src = bbox + (size_t)(i * NS + j0 + r) * 128 + u * 4;
            gld_lds16(src, dst + w * 256);
        }
    };

    auto compute = [&](int t, int buf) {
        const float* tile = &lds[wave][buf][0];
        const int j0 = jq + t * 16;
        const int x = lr & 7;
        #pragma unroll
        for (int b2 = 0; b2 < 2; ++b2) {
            const float mk = mask[b2 * NS + j0 + lr];
            f32x4 c = (f32x4){0.f, 0.f, 0.f, 0.f};
            #pragma unroll
            for (int kk = 0; kk < 2; ++kk) {
                const int q0 = b2 * 16 + kk * 8 + lg * 2;
                f32x4 ca = *reinterpret_cast<const f32x4*>(tile + (size_t)(lr * 32 + ((q0)     ^ x)) * 4);
                f32x4 cb = *reinterpret_cast<const f32x4*>(tile + (size_t)(lr * 32 + ((q0 + 1) ^ x)) * 4);
                short8 bf;
                bf[0] = f2bf(ca[0]); bf[1] = f2bf(ca[1]); bf[2] = f2bf(ca[2]); bf[3] = f2bf(ca[3]);
                bf[4] = f2bf(cb[0]); bf[5] = f2bf(cb[1]); bf[6] = f2bf(cb[2]); bf[7] = f2bf(cb[3]);
                c = MFMA(qa[b2][kk], bf, c);
            }
            if (lg < 3) {
                #pragma unroll
                for (int r = 0; r < 4; ++r) {
                    const int n = lg * 4 + r;
                    biasH[((size_t)(b2 * NHEAD + n) * NS + i) * NS + j0 + lr] =
                        f2bf(c[r] * 0.125f + mk);
                }
            }
        }
    };

    stage(0, 0);
    for (int t = 0; t < 16; ++t) {
        const int buf = t & 1;
        asm volatile("s_waitcnt lgkmcnt(0)" ::: "memory");
        if (t < 15) stage(t + 1, buf ^ 1);
        if (t == 0 || t == 15) asm volatile("s_waitcnt vmcnt(8)"  ::: "memory");
        else                   asm volatile("s_waitcnt vmcnt(16)" ::: "memory");
        compute(t, buf);
    }
}

// ---------------------------------------------------------------------------
// Kernel 3: attn3 v2 — LDS-staged attention with 3-buffer rotation +
// counted vmcnt + raw barrier (loads in flight across barriers).
// ---------------------------------------------------------------------------
__global__ __launch_bounds__(256, 3) void attn3(
    const short* __restrict__ Q,
    const short* __restrict__ K,
    const short* __restrict__ VT,
    const short* __restrict__ biasH,
    float* __restrict__ out)
{
    const int tid = threadIdx.x;
    const int lane = tid & 63;
    const int wave = tid >> 6;
    const int lg = lane >> 4, lr = lane & 15;

    const int wgid = xcd_swz(blockIdx.x, 24 * 16);
    const int bh = wgid >> 4;
    const int ic = wgid & 15;
    const int b = bh / NHEAD, h = bh % NHEAD;
    const int i0 = ic * 64 + wave * 16;

    __shared__ short Klds[3][2048];
    __shared__ short Vlds[3][2048];
    __shared__ short Blds[3][2048];
    __shared__ short plds[4][16 * 40];

    short8 qa[2];
    #pragma unroll
    for (int kk = 0; kk < 2; ++kk)
        qa[kk] = *reinterpret_cast<const short8*>(
            Q + ((size_t)(b * NS) + i0 + lr) * NHID + h * 64 + kk * 32 + lg * 8);

    const short* Kb = K + (size_t)b * NS * NHID + h * 64;
    const short* Vb = VT + (size_t)(b * NHEAD + h) * NDH * NS;
    const short* Bb = biasH + ((size_t)(b * NHEAD + h) * NS + ic * 64) * NS;

    f32x4 ctx[4];
    #pragma unroll
    for (int dt = 0; dt < 4; ++dt) ctx[dt] = (f32x4){0.f, 0.f, 0.f, 0.f};
    f32x4 den = (f32x4){0.f, 0.f, 0.f, 0.f};

    const int kr = tid >> 3, ku = tid & 7;
    const int kgu = ku ^ (kr & 7);
    const int vr = tid >> 2, vu = tid & 3;
    const int vgu = vu ^ (vr & 3);
    const int br = tid >> 2, bu = tid & 3;

    auto stage = [&](int t, int buf) {
        const int j0 = t * 32;
        gld_lds16s(Kb + (size_t)(j0 + kr) * NHID + kgu * 8, &Klds[buf][tid * 8]);
        gld_lds16s(Vb + (size_t)vr * NS + j0 + vgu * 8,     &Vlds[buf][tid * 8]);
        gld_lds16s(Bb + (size_t)br * NS + j0 + bu * 8,      &Blds[buf][tid * 8]);
    };

    auto compute = [&](int buf) {
        f32x4 sc[2];
        #pragma unroll
        for (int s = 0; s < 2; ++s) {
            f32x4 c = (f32x4){0.f, 0.f, 0.f, 0.f};
            #pragma unroll
            for (int kk = 0; kk < 2; ++kk) {
                const int R = s * 16 + lr;
                const int U = kk * 4 + lg;
                short8 kf = *reinterpret_cast<const short8*>(
                    &Klds[buf][(R * 8 + (U ^ (R & 7))) * 8]);
                c = MFMA(qa[kk], kf, c);
            }
            sc[s] = c;
        }
        #pragma unroll
        for (int s = 0; s < 2; ++s)
            #pragma unroll
            for (int r = 0; r < 4; ++r) {
                const unsigned int u = (unsigned int)(unsigned short)
                    Blds[buf][wave * 512 + (lg * 4 + r) * 32 + s * 16 + lr] << 16;
                float bb;
                __builtin_memcpy(&bb, &u, 4);
                sc[s][r] = __expf(sc[s][r] * 0.125f + bb);
            }
        den += sc[0] + sc[1];

        #pragma unroll
        for (int s = 0; s < 2; ++s)
            #pragma unroll
            for (int r = 0; r < 4; ++r)
                plds[wave][(lg * 4 + r) * 40 + s * 16 + lr] = f2bf(sc[s][r]);
        asm volatile("" ::: "memory");
        short8 pa = *reinterpret_cast<const short8*>(&plds[wave][lr * 40 + lg * 8]);
        asm volatile("" ::: "memory");

        #pragma unroll
        for (int dt = 0; dt < 4; ++dt) {
            const int R = dt * 16 + lr;
            short8 vf = *reinterpret_cast<const short8*>(
                &Vlds[buf][(R * 4 + (lg ^ (R & 3))) * 8]);
            ctx[dt] = MFMA(pa, vf, ctx[dt]);
        }
    };

    stage(0, 0);
    for (int t = 0; t < 32; ++t) {
        if (t < 31) {
            stage(t + 1, (t + 1) % 3);
            asm volatile("s_waitcnt vmcnt(3)" ::: "memory");
        } else {
            asm volatile("s_waitcnt vmcnt(0)" ::: "memory");
        }
        __builtin_amdgcn_s_barrier();
        compute(t % 3);
    }

    #pragma unroll
    for (int w = 1; w < 16; w <<= 1) {
        f32x4 o;
        #pragma unroll
        for (int r = 0; r < 4; ++r) o[r] = __shfl_xor(den[r], w, 64);
        den += o;
    }

    #pragma unroll
    for (int r = 0; r < 4; ++r) {
        const float inv = 1.0f / den[r];
        const int i = i0 + lg * 4 + r;
        #pragma unroll
        for (int dt = 0; dt < 4; ++dt)
            out[((size_t)(b * NS) + i) * NHID + h * 64 + dt * 16 + lr] =
                ctx[dt][r] * inv;
    }
}

extern "C" void kernel_launch(void* const* d_in, const int* in_sizes, int n_in,
                              void* d_out, int out_size, void* d_ws, size_t ws_size,
                              hipStream_t stream) {
    (void)in_sizes; (void)n_in; (void)out_size; (void)ws_size;
    const float* hidden = (const float*)d_in[0];
    const float* bbox   = (const float*)d_in[1];
    const float* mask   = (const float*)d_in[2];
    const float* Wq = (const float*)d_in[3]; const float* bq = (const float*)d_in[4];
    const float* Wk = (const float*)d_in[5]; const float* bk = (const float*)d_in[6];
    const float* Wv = (const float*)d_in[7]; const float* bv = (const float*)d_in[8];
    float* out = (float*)d_out;

    char* ws = (char*)d_ws;
    const size_t qkv_bytes = (size_t)NB * NS * NHID * sizeof(short);
    short* Qw  = (short*)ws;
    short* Kw  = (short*)(ws + qkv_bytes);
    short* VTw = (short*)(ws + 2 * qkv_bytes);
    short* biasH = (short*)(ws + 3 * qkv_bytes);
    const size_t bias_bytes = (size_t)NB * NHEAD * NS * NS * sizeof(short);
    short* Xbf = (short*)(ws + 3 * qkv_bytes + bias_bytes);
    short* Wbf = Xbf + (size_t)2048 * NHID;

    const int cvt_total = (NHE + 3 * WE) / 4;
    cvt_bf16_all<<<cvt_total / 256, 256, 0, stream>>>(hidden, Wq, Wk, Wv, Xbf, Wbf);

    qkv_gemm<<<32 * 36, 256, 0, stream>>>(Xbf, Wbf, bq, bk, bv, Qw, Kw, VTw);

    bias_gemm<<<NS, 256, 0, stream>>>(Qw, bbox, mask, biasH);

    attn3<<<24 * 16, 256, 0, stream>>>(Qw, Kw, VTw, biasH, out);
}

// Round 16
// 191.342 us; speedup vs baseline: 6.9054x; 1.0864x over previous
//
#include <hip/hip_runtime.h>
#include <hip/hip_bf16.h>

typedef short bf4 __attribute__((ext_vector_type(4)));
typedef short short8 __attribute__((ext_vector_type(8)));
typedef float f32x4 __attribute__((ext_vector_type(4)));

#define MFMA(a, b, c) __builtin_amdgcn_mfma_f32_16x16x32_bf16((a), (b), (c), 0, 0, 0)

#define NB 2
#define NS 1024
#define NHID 768
#define NHEAD 12
#define NDH 64

__device__ __forceinline__ short f2bf(float x) {
    __hip_bfloat16 h = __float2bfloat16(x);
    return *reinterpret_cast<short*>(&h);
}

__device__ __forceinline__ int xcd_swz(int orig, int nwg) {
    return (orig & 7) * (nwg >> 3) + (orig >> 3);
}

typedef const __attribute__((address_space(1))) void gas_t;
typedef __attribute__((address_space(3))) void las_t;
__device__ __forceinline__ void gld_lds16(const float* g, float* l) {
    __builtin_amdgcn_global_load_lds((gas_t*)g, (las_t*)l, 16, 0, 0);
}
__device__ __forceinline__ void gld_lds16s(const short* g, short* l) {
    __builtin_amdgcn_global_load_lds((gas_t*)g, (las_t*)l, 16, 0, 0);
}

// ---------------------------------------------------------------------------
// Kernel 0: convert hidden + Wq/Wk/Wv to bf16 (once).
// ---------------------------------------------------------------------------
#define NHE (2048 * 768)
#define WE  (768 * 768)
__global__ void cvt_bf16_all(
    const float* __restrict__ hidden,
    const float* __restrict__ Wq, const float* __restrict__ Wk,
    const float* __restrict__ Wv,
    short* __restrict__ Xbf, short* __restrict__ Wbf)
{
    const int base = (blockIdx.x * 256 + threadIdx.x) * 4;
    const float* src; short* dst; int off;
    if (base < NHE)               { src = hidden; dst = Xbf;          off = base; }
    else if (base < NHE + WE)     { src = Wq;     dst = Wbf;          off = base - NHE; }
    else if (base < NHE + 2 * WE) { src = Wk;     dst = Wbf + WE;     off = base - NHE - WE; }
    else                          { src = Wv;     dst = Wbf + 2 * WE; off = base - NHE - 2 * WE; }
    f32x4 v = *reinterpret_cast<const f32x4*>(src + off);
    bf4 r;
    r[0] = f2bf(v[0]); r[1] = f2bf(v[1]); r[2] = f2bf(v[2]); r[3] = f2bf(v[3]);
    *reinterpret_cast<bf4*>(dst + off) = r;
}

// ---------------------------------------------------------------------------
// Shared GEMM block body (R14-verified): BM=64 BN=64 BK=64, 4 waves,
// 3-buffer LDS rotation + counted vmcnt + raw barrier. n0 in [0,2304).
// ---------------------------------------------------------------------------
__device__ __forceinline__ void qkv_block(
    int m0, int n0,
    const short* __restrict__ Xbf, const short* __restrict__ Wbf,
    const float* __restrict__ bq, const float* __restrict__ bk,
    const float* __restrict__ bv,
    short* __restrict__ Qo, short* __restrict__ Ko, short* __restrict__ VTo,
    short (*Alds)[4096], short (*Blds)[4096])
{
    const int lane = threadIdx.x & 63;
    const int wave = threadIdx.x >> 6;
    const int lg = lane >> 4, lr = lane & 15;

    const int proj = n0 / NHID;
    const int ncol0 = n0 % NHID;
    const float* bias = proj == 0 ? bq : (proj == 1 ? bk : bv);

    f32x4 acc[4];
    #pragma unroll
    for (int s = 0; s < 4; ++s) acc[s] = (f32x4){0.f, 0.f, 0.f, 0.f};

    auto stage = [&](int t, int buf) {
        const int k0 = t * 64;
        #pragma unroll
        for (int p = 0; p < 2; ++p) {
            const int op = wave * 2 + p;
            const int unit = op * 64 + lane;
            const int r = unit >> 3, u = unit & 7;
            const int g = u ^ (r & 7);
            gld_lds16s(Xbf + (size_t)(m0 + r) * NHID + k0 + g * 8,
                       &Alds[buf][op * 512]);
        }
        #pragma unroll
        for (int p = 0; p < 2; ++p) {
            const int op = wave * 2 + p;
            const int unit = op * 64 + lane;
            const int r = unit >> 3, u = unit & 7;
            const int g = u ^ (r & 7);
            gld_lds16s(Wbf + (size_t)(n0 + r) * NHID + k0 + g * 8,
                       &Blds[buf][op * 512]);
        }
    };

    auto compute = [&](int buf) {
        #pragma unroll
        for (int kk = 0; kk < 2; ++kk) {
            const int U = kk * 4 + lg;
            const int Ra = wave * 16 + lr;
            short8 a = *reinterpret_cast<const short8*>(
                &Alds[buf][(Ra * 8 + (U ^ (Ra & 7))) * 8]);
            #pragma unroll
            for (int s = 0; s < 4; ++s) {
                const int R = s * 16 + lr;
                short8 b = *reinterpret_cast<const short8*>(
                    &Blds[buf][(R * 8 + (U ^ (R & 7))) * 8]);
                acc[s] = MFMA(a, b, acc[s]);
            }
        }
    };

    stage(0, 0);
    for (int t = 0; t < 12; ++t) {
        if (t < 11) {
            stage(t + 1, (t + 1) % 3);
            asm volatile("s_waitcnt vmcnt(4)" ::: "memory");
        } else {
            asm volatile("s_waitcnt vmcnt(0)" ::: "memory");
        }
        __builtin_amdgcn_s_barrier();
        compute(t % 3);
    }

    #pragma unroll
    for (int s = 0; s < 4; ++s) {
        const int ncol = ncol0 + s * 16 + lr;
        const float badd = bias[ncol];
        #pragma unroll
        for (int r = 0; r < 4; ++r) {
            const int m = m0 + wave * 16 + lg * 4 + r;
            const short v16 = f2bf(acc[s][r] + badd);
            if (proj == 0) {
                Qo[(size_t)m * NHID + ncol] = v16;
            } else if (proj == 1) {
                Ko[(size_t)m * NHID + ncol] = v16;
            } else {
                const int b = m >> 10, ss = m & 1023;
                const int h = ncol >> 6, dd = ncol & 63;
                VTo[(((size_t)(b * NHEAD + h) * NDH + dd) << 10) + ss] = v16;
            }
        }
    }
}

// ---------------------------------------------------------------------------
// Bias block body (R14-verified): one i row, both b, bf16 pre-scaled+mask.
// ---------------------------------------------------------------------------
__device__ __forceinline__ void bias_block(
    int i,
    const short* __restrict__ Q,
    const float* __restrict__ bbox,
    const float* __restrict__ mask,
    short* __restrict__ biasH,
    float (*lds)[2][2048])
{
    const int lane = threadIdx.x & 63;
    const int wave = threadIdx.x >> 6;
    const int lg = lane >> 4, lr = lane & 15;
    const int jq = wave * 256;

    short8 qa[2][2];
    #pragma unroll
    for (int b2 = 0; b2 < 2; ++b2)
        #pragma unroll
        for (int kk = 0; kk < 2; ++kk)
            qa[b2][kk] = *reinterpret_cast<const short8*>(
                Q + ((size_t)(b2 * NS) + i) * NHID + lr * 64 + kk * 32 + lg * 8);

    const int r_half = lane >> 5;
    const int u_lin = lane & 31;

    auto stage = [&](int t, int buf) {
        const int j0 = jq + t * 16;
        float* dst = &lds[wave][buf][0];
        #pragma unroll
        for (int w = 0; w < 8; ++w) {
            const int r = 2 * w + r_half;
            const int u = u_lin ^ (r & 7);
            const float* src = bbox + (size_t)(i * NS + j0 + r) * 128 + u * 4;
            gld_lds16(src, dst + w * 256);
        }
    };

    auto compute = [&](int t, int buf) {
        const float* tile = &lds[wave][buf][0];
        const int j0 = jq + t * 16;
        const int x = lr & 7;
        #pragma unroll
        for (int b2 = 0; b2 < 2; ++b2) {
            const float mk = mask[b2 * NS + j0 + lr];
            f32x4 c = (f32x4){0.f, 0.f, 0.f, 0.f};
            #pragma unroll
            for (int kk = 0; kk < 2; ++kk) {
                const int q0 = b2 * 16 + kk * 8 + lg * 2;
                f32x4 ca = *reinterpret_cast<const f32x4*>(tile + (size_t)(lr * 32 + ((q0)     ^ x)) * 4);
                f32x4 cb = *reinterpret_cast<const f32x4*>(tile + (size_t)(lr * 32 + ((q0 + 1) ^ x)) * 4);
                short8 bf;
                bf[0] = f2bf(ca[0]); bf[1] = f2bf(ca[1]); bf[2] = f2bf(ca[2]); bf[3] = f2bf(ca[3]);
                bf[4] = f2bf(cb[0]); bf[5] = f2bf(cb[1]); bf[6] = f2bf(cb[2]); bf[7] = f2bf(cb[3]);
                c = MFMA(qa[b2][kk], bf, c);
            }
            if (lg < 3) {
                #pragma unroll
                for (int r = 0; r < 4; ++r) {
                    const int n = lg * 4 + r;
                    biasH[((size_t)(b2 * NHEAD + n) * NS + i) * NS + j0 + lr] =
                        f2bf(c[r] * 0.125f + mk);
                }
            }
        }
    };

    stage(0, 0);
    for (int t = 0; t < 16; ++t) {
        const int buf = t & 1;
        asm volatile("s_waitcnt lgkmcnt(0)" ::: "memory");
        if (t < 15) stage(t + 1, buf ^ 1);
        if (t == 0 || t == 15) asm volatile("s_waitcnt vmcnt(8)"  ::: "memory");
        else                   asm volatile("s_waitcnt vmcnt(16)" ::: "memory");
        compute(t, buf);
    }
}

// ---------------------------------------------------------------------------
// Kernel 1: Q-projection only (n in [0,768)). 384 blocks, XCD-swizzled.
// ---------------------------------------------------------------------------
__global__ __launch_bounds__(256, 3) void q_gemm(
    const short* __restrict__ Xbf, const short* __restrict__ Wbf,
    const float* __restrict__ bq, const float* __restrict__ bk,
    const float* __restrict__ bv,
    short* __restrict__ Qo, short* __restrict__ Ko, short* __restrict__ VTo)
{
    __shared__ short Alds[3][4096];
    __shared__ short Blds[3][4096];
    const int s = xcd_swz(blockIdx.x, 384);
    const int m0 = (s / 12) * 64;
    const int n0 = (s % 12) * 64;
    qkv_block(m0, n0, Xbf, Wbf, bq, bk, bv, Qo, Ko, VTo, Alds, Blds);
}

// ---------------------------------------------------------------------------
// Kernel 2 (FAT): bias (1024 blocks) + K/V projection (768 blocks) fused in
// one heterogeneous grid (1792 = 7*256; bid%7<4 -> bias, else KV). KV compute
// hides inside bias's fetch-bound window.
// ---------------------------------------------------------------------------
__global__ __launch_bounds__(256, 2) void bias_kv(
    const short* __restrict__ Qw,
    const float* __restrict__ bbox,
    const float* __restrict__ mask,
    short* __restrict__ biasH,
    const short* __restrict__ Xbf, const short* __restrict__ Wbf,
    const float* __restrict__ bq, const float* __restrict__ bk,
    const float* __restrict__ bv,
    short* __restrict__ Ko, short* __restrict__ VTo)
{
    __shared__ __align__(16) char smem[65536];
    const int bid = blockIdx.x;
    const int grp = bid / 7, rem = bid % 7;
    if (rem < 4) {
        const int i = grp * 4 + rem;                 // 0..1023
        bias_block(i, Qw, bbox, mask, biasH, (float(*)[2][2048])smem);
    } else {
        const int kvid = grp * 3 + (rem - 4);        // 0..767
        const int s = xcd_swz(kvid, 768);
        const int m0 = (s / 24) * 64;
        const int n0 = NHID + (s % 24) * 64;         // [768, 2304)
        qkv_block(m0, n0, Xbf, Wbf, bq, bk, bv,
                  nullptr, Ko, VTo,
                  (short(*)[4096])smem, (short(*)[4096])(smem + 24576));
    }
}

// ---------------------------------------------------------------------------
// Kernel 3: attn3 (R14 version, unchanged).
// ---------------------------------------------------------------------------
__global__ __launch_bounds__(256, 3) void attn3(
    const short* __restrict__ Q,
    const short* __restrict__ K,
    const short* __restrict__ VT,
    const short* __restrict__ biasH,
    float* __restrict__ out)
{
    const int tid = threadIdx.x;
    const int lane = tid & 63;
    const int wave = tid >> 6;
    const int lg = lane >> 4, lr = lane & 15;

    const int wgid = xcd_swz(blockIdx.x, 24 * 16);
    const int bh = wgid >> 4;
    const int ic = wgid & 15;
    const int b = bh / NHEAD, h = bh % NHEAD;
    const int i0 = ic * 64 + wave * 16;

    __shared__ short Klds[3][2048];
    __shared__ short Vlds[3][2048];
    __shared__ short Blds[3][2048];
    __shared__ short plds[4][16 * 40];

    short8 qa[2];
    #pragma unroll
    for (int kk = 0; kk < 2; ++kk)
        qa[kk] = *reinterpret_cast<const short8*>(
            Q + ((size_t)(b * NS) + i0 + lr) * NHID + h * 64 + kk * 32 + lg * 8);

    const short* Kb = K + (size_t)b * NS * NHID + h * 64;
    const short* Vb = VT + (size_t)(b * NHEAD + h) * NDH * NS;
    const short* Bb = biasH + ((size_t)(b * NHEAD + h) * NS + ic * 64) * NS;

    f32x4 ctx[4];
    #pragma unroll
    for (int dt = 0; dt < 4; ++dt) ctx[dt] = (f32x4){0.f, 0.f, 0.f, 0.f};
    f32x4 den = (f32x4){0.f, 0.f, 0.f, 0.f};

    const int kr = tid >> 3, ku = tid & 7;
    const int kgu = ku ^ (kr & 7);
    const int vr = tid >> 2, vu = tid & 3;
    const int vgu = vu ^ (vr & 3);
    const int br = tid >> 2, bu = tid & 3;

    auto stage = [&](int t, int buf) {
        const int j0 = t * 32;
        gld_lds16s(Kb + (size_t)(j0 + kr) * NHID + kgu * 8, &Klds[buf][tid * 8]);
        gld_lds16s(Vb + (size_t)vr * NS + j0 + vgu * 8,     &Vlds[buf][tid * 8]);
        gld_lds16s(Bb + (size_t)br * NS + j0 + bu * 8,      &Blds[buf][tid * 8]);
    };

    auto compute = [&](int buf) {
        f32x4 sc[2];
        #pragma unroll
        for (int s = 0; s < 2; ++s) {
            f32x4 c = (f32x4){0.f, 0.f, 0.f, 0.f};
            #pragma unroll
            for (int kk = 0; kk < 2; ++kk) {
                const int R = s * 16 + lr;
                const int U = kk * 4 + lg;
                short8 kf = *reinterpret_cast<const short8*>(
                    &Klds[buf][(R * 8 + (U ^ (R & 7))) * 8]);
                c = MFMA(qa[kk], kf, c);
            }
            sc[s] = c;
        }
        #pragma unroll
        for (int s = 0; s < 2; ++s)
            #pragma unroll
            for (int r = 0; r < 4; ++r) {
                const unsigned int u = (unsigned int)(unsigned short)
                    Blds[buf][wave * 512 + (lg * 4 + r) * 32 + s * 16 + lr] << 16;
                float bb;
                __builtin_memcpy(&bb, &u, 4);
                sc[s][r] = __expf(sc[s][r] * 0.125f + bb);
            }
        den += sc[0] + sc[1];

        #pragma unroll
        for (int s = 0; s < 2; ++s)
            #pragma unroll
            for (int r = 0; r < 4; ++r)
                plds[wave][(lg * 4 + r) * 40 + s * 16 + lr] = f2bf(sc[s][r]);
        asm volatile("" ::: "memory");
        short8 pa = *reinterpret_cast<const short8*>(&plds[wave][lr * 40 + lg * 8]);
        asm volatile("" ::: "memory");

        #pragma unroll
        for (int dt = 0; dt < 4; ++dt) {
            const int R = dt * 16 + lr;
            short8 vf = *reinterpret_cast<const short8*>(
                &Vlds[buf][(R * 4 + (lg ^ (R & 3))) * 8]);
            ctx[dt] = MFMA(pa, vf, ctx[dt]);
        }
    };

    stage(0, 0);
    for (int t = 0; t < 32; ++t) {
        if (t < 31) {
            stage(t + 1, (t + 1) % 3);
            asm volatile("s_waitcnt vmcnt(3)" ::: "memory");
        } else {
            asm volatile("s_waitcnt vmcnt(0)" ::: "memory");
        }
        __builtin_amdgcn_s_barrier();
        compute(t % 3);
    }

    #pragma unroll
    for (int w = 1; w < 16; w <<= 1) {
        f32x4 o;
        #pragma unroll
        for (int r = 0; r < 4; ++r) o[r] = __shfl_xor(den[r], w, 64);
        den += o;
    }

    #pragma unroll
    for (int r = 0; r < 4; ++r) {
        const float inv = 1.0f / den[r];
        const int i = i0 + lg * 4 + r;
        #pragma unroll
        for (int dt = 0; dt < 4; ++dt)
            out[((size_t)(b * NS) + i) * NHID + h * 64 + dt * 16 + lr] =
                ctx[dt][r] * inv;
    }
}

extern "C" void kernel_launch(void* const* d_in, const int* in_sizes, int n_in,
                              void* d_out, int out_size, void* d_ws, size_t ws_size,
                              hipStream_t stream) {
    (void)in_sizes; (void)n_in; (void)out_size; (void)ws_size;
    const float* hidden = (const float*)d_in[0];
    const float* bbox   = (const float*)d_in[1];
    const float* mask   = (const float*)d_in[2];
    const float* Wq = (const float*)d_in[3]; const float* bq = (const float*)d_in[4];
    const float* Wk = (const float*)d_in[5]; const float* bk = (const float*)d_in[6];
    const float* Wv = (const float*)d_in[7]; const float* bv = (const float*)d_in[8];
    float* out = (float*)d_out;

    char* ws = (char*)d_ws;
    const size_t qkv_bytes = (size_t)NB * NS * NHID * sizeof(short);
    short* Qw  = (short*)ws;
    short* Kw  = (short*)(ws + qkv_bytes);
    short* VTw = (short*)(ws + 2 * qkv_bytes);
    short* biasH = (short*)(ws + 3 * qkv_bytes);
    const size_t bias_bytes = (size_t)NB * NHEAD * NS * NS * sizeof(short);
    short* Xbf = (short*)(ws + 3 * qkv_bytes + bias_bytes);
    short* Wbf = Xbf + (size_t)2048 * NHID;

    const int cvt_total = (NHE + 3 * WE) / 4;
    cvt_bf16_all<<<cvt_total / 256, 256, 0, stream>>>(hidden, Wq, Wk, Wv, Xbf, Wbf);

    q_gemm<<<384, 256, 0, stream>>>(Xbf, Wbf, bq, bk, bv, Qw, Kw, VTw);

    bias_kv<<<1792, 256, 0, stream>>>(Qw, bbox, mask, biasH,
                                      Xbf, Wbf, bq, bk, bv, Kw, VTw);

    attn3<<<24 * 16, 256, 0, stream>>>(Qw, Kw, VTw, biasH, out);
}